// Round 5
// baseline (170.073 us; speedup 1.0000x reference)
//
#include <hip/hip_runtime.h>
#include <hip/hip_bf16.h>

// Single-head causal attention, B=4 T=4096 C=1024 H=128, fp32 in/out.
//  K1 wtrans: W[1024][128] f32 -> Wt[mat][128][1024] bf16 (transposed)
//  K2 proj:   GEMM BM=64 BN=128 BK=64, 64x64 WAVE-TILES (4 accs), reg prefetch.
//  K3 attn:   split-K causal attention, 8-wave 512-thr blocks, 256-row strips,
//             NWORK=136, exactly 4 key-tiles/item. R16:
//             (a) LDS swizzle XOR-8 -> ROTATION-16 (unit u of row r at
//                 (u+r)&15; V dims paired 2-per-256B-row). R4's XOR-8 gave
//                 4 lanes per bank-group per 32-lane phase = 4-way conflict
//                 (2.12M deterministic conflicts); rotation-16 gives 2-way=free
//                 (same mechanism as R0's +8 pad, which measured 0).
//             (b) split waits: vmcnt(2)[K]->bar->(issue nextK)->QK/softmax->
//                 vmcnt[V]->bar->(issue nextV)->PV. V latency hides under QK.
//             (c) epilogue: reuse dead K/V LDS as per-wave [32][128] transpose
//                 buffer -> Opart stored as full-line coalesced bf16x8 (kills
//                 ~35MB write-allocate RMW fetch that was ~all of FETCH_SIZE).
//             R12 lesson: reg-prefetch -> VGPR cliff. R13 lesson: NEVER pass a
//             2nd arg to __launch_bounds__ (64-VGPR spill disaster).
//             Partials: bf16 Opart + f32 Lpart plain stores (NO atomics).
//  K4 reduce: sum bf16 partials over splits, normalize, write f32 out.

#define TSEQ 4096
#define NBATCH 4
#define CEMB 1024
#define HS 128
#define NWORK 136   // sum over q0=0..15 of (q0+1)

typedef float  f32x4  __attribute__((ext_vector_type(4)));
typedef float  f32x16 __attribute__((ext_vector_type(16)));
typedef __bf16 bf16x4 __attribute__((ext_vector_type(4)));
typedef __bf16 bf16x8 __attribute__((ext_vector_type(8)));
typedef int    i32x2  __attribute__((ext_vector_type(2)));
typedef int    i32x4  __attribute__((ext_vector_type(4)));

__device__ __forceinline__ __bf16 f2b(float f) { return (__bf16)f; }
__device__ __forceinline__ float fexp2(float f) { return __builtin_amdgcn_exp2f(f); }

typedef const __attribute__((address_space(1))) void* gas_ptr;
typedef __attribute__((address_space(3))) void* las_ptr;
__device__ __forceinline__ void gload16(const void* g, void* l) {
  __builtin_amdgcn_global_load_lds((gas_ptr)g, (las_ptr)l, 16, 0, 0);
}

// ---------------------------------------------------------------------------
__global__ void wtrans_kernel(const float* __restrict__ Wq,
                              const float* __restrict__ Wk,
                              const float* __restrict__ Wv,
                              __bf16* __restrict__ Wt) {
  const float* W = (blockIdx.y == 0) ? Wq : (blockIdx.y == 1) ? Wk : Wv;
  int g  = blockIdx.x * 256 + threadIdx.x;
  int n  = g & 127;
  int k0 = (g >> 7) * 8;
  bf16x8 v;
#pragma unroll
  for (int i = 0; i < 8; ++i) v[i] = f2b(W[(size_t)(k0 + i) * HS + n]);
  *(bf16x8*)(Wt + (size_t)blockIdx.y * HS * CEMB + (size_t)n * CEMB + k0) = v;
}

// ---------------------------------------------------------------------------
// K2: projection GEMM v8. grid 768 x 128 thr (2 waves).
__global__ __launch_bounds__(128)
void proj_kernel(const float* __restrict__ x, const __bf16* __restrict__ Wt,
                 __bf16* __restrict__ qb, __bf16* __restrict__ kb,
                 __bf16* __restrict__ vt) {
  __shared__ __align__(16) __bf16 As[64 * 72];    // x tile  [64 m][64 k] pad +8
  __shared__ __align__(16) __bf16 Bs[128 * 72];   // Wt tile [128 n][64 k] pad +8

  const int tid  = threadIdx.x;
  const int lane = tid & 63;
  const int w    = tid >> 6;        // 0..1
  const int l31  = lane & 31;
  const int half = lane >> 5;

  const int bid   = blockIdx.x;
  const int xcd   = bid & 7;
  const int rest  = bid >> 3;
  const int mat   = rest % 3;
  const int mslab = rest / 3;
  const int m0    = (xcd + 8 * mslab) * 64;
  const __bf16* Wm = Wt + (size_t)mat * HS * CEMB;

  f32x16 acc[2][2];   // [mi][ni]
#pragma unroll
  for (int a = 0; a < 2; ++a)
#pragma unroll
    for (int b = 0; b < 2; ++b)
#pragma unroll
      for (int r = 0; r < 16; ++r) acc[a][b][r] = 0.f;

  const int srow = tid >> 3;    // 0..15 (16 rows per pass)
  const int soff = tid & 7;     // 16B unit within a 128B row

  // ---- prefetch tile 0 into registers ----
  f32x4  pa[4][2];
  bf16x8 pb[8];
#pragma unroll
  for (int i = 0; i < 4; ++i) {
    const float* p = x + (size_t)(m0 + srow + 16 * i) * CEMB + soff * 8;
    pa[i][0] = *(const f32x4*)p;
    pa[i][1] = *(const f32x4*)(p + 4);
  }
#pragma unroll
  for (int i = 0; i < 8; ++i)
    pb[i] = *(const bf16x8*)(Wm + (size_t)(srow + 16 * i) * CEMB + soff * 8);

  for (int ks = 0; ks < CEMB; ks += 64) {
    __syncthreads();
    // ---- stage phase: write already-resident regs to LDS ----
#pragma unroll
    for (int i = 0; i < 4; ++i) {
      bf16x8 h;
#pragma unroll
      for (int j = 0; j < 4; ++j) {
        h[j]     = f2b(pa[i][0][j]);
        h[4 + j] = f2b(pa[i][1][j]);
      }
      *(bf16x8*)(As + (srow + 16 * i) * 72 + soff * 8) = h;
    }
#pragma unroll
    for (int i = 0; i < 8; ++i)
      *(bf16x8*)(Bs + (srow + 16 * i) * 72 + soff * 8) = pb[i];
    __syncthreads();
    // ---- prefetch next tile (overlaps MFMA phase) ----
    if (ks + 64 < CEMB) {
#pragma unroll
      for (int i = 0; i < 4; ++i) {
        const float* p = x + (size_t)(m0 + srow + 16 * i) * CEMB + ks + 64 + soff * 8;
        pa[i][0] = *(const f32x4*)p;
        pa[i][1] = *(const f32x4*)(p + 4);
      }
#pragma unroll
      for (int i = 0; i < 8; ++i)
        pb[i] = *(const bf16x8*)(Wm + (size_t)(srow + 16 * i) * CEMB + ks + 64 + soff * 8);
    }
    // ---- MFMA: 16 per wave per k-step; 4 MFMA per 4 frag-reads ----
#pragma unroll
    for (int kc = 0; kc < 4; ++kc) {
      bf16x8 af[2], bf[2];
#pragma unroll
      for (int mi = 0; mi < 2; ++mi)
        af[mi] = *(const bf16x8*)(As + (mi * 32 + l31) * 72 + kc * 16 + half * 8);
#pragma unroll
      for (int ni = 0; ni < 2; ++ni)
        bf[ni] = *(const bf16x8*)(Bs + (64 * w + ni * 32 + l31) * 72 + kc * 16 + half * 8);
#pragma unroll
      for (int mi = 0; mi < 2; ++mi)
#pragma unroll
        for (int ni = 0; ni < 2; ++ni)
          acc[mi][ni] = __builtin_amdgcn_mfma_f32_32x32x16_bf16(
              af[mi], bf[ni], acc[mi][ni], 0, 0, 0);
    }
  }

  // epilogue: n = 64w + ni*32 + l31, m = m0 + mi*32 + (r&3)+8*(r>>2)+4*half
  const float qscale = 1.4426950408889634f / 32.0f;  // log2e / sqrt(1024)
  if (mat == 0) {
#pragma unroll
    for (int mi = 0; mi < 2; ++mi)
#pragma unroll
      for (int ni = 0; ni < 2; ++ni) {
        int n = 64 * w + ni * 32 + l31;
#pragma unroll
        for (int r = 0; r < 16; ++r) {
          int m = m0 + mi * 32 + (r & 3) + 8 * (r >> 2) + 4 * half;
          qb[(size_t)m * HS + n] = f2b(acc[mi][ni][r] * qscale);
        }
      }
  } else if (mat == 1) {
#pragma unroll
    for (int mi = 0; mi < 2; ++mi)
#pragma unroll
      for (int ni = 0; ni < 2; ++ni) {
        int n = 64 * w + ni * 32 + l31;
#pragma unroll
        for (int r = 0; r < 16; ++r) {
          int m = m0 + mi * 32 + (r & 3) + 8 * (r >> 2) + 4 * half;
          kb[(size_t)m * HS + n] = f2b(acc[mi][ni][r]);
        }
      }
  } else {
    const int bt = m0 >> 12;
#pragma unroll
    for (int mi = 0; mi < 2; ++mi)
#pragma unroll
      for (int ni = 0; ni < 2; ++ni) {
        int n = 64 * w + ni * 32 + l31;
#pragma unroll
        for (int g = 0; g < 4; ++g) {
          bf16x4 pk;
#pragma unroll
          for (int d = 0; d < 4; ++d) pk[d] = f2b(acc[mi][ni][4 * g + d]);
          int tl = ((m0 + mi * 32) & 4095) + 8 * g + 4 * half;
          *(bf16x4*)(vt + ((size_t)bt * HS + n) * TSEQ + tl) = pk;
        }
      }
  }
}

// ---------------------------------------------------------------------------
// K3: split-K causal attention. grid (136,4) x 512 thr (8 waves).
// LDS 64KB: S[0..8191] Kt buf0 | S[8192..] Kt buf1 | +16384 Vt buf0/buf1.
// K rotation-16: unit u of key-row r stored at (u+r)&15 (16 units/256B row).
// V pairing: dims (2j,2j+1) share 256B row j; unit (d&1)*8+u stored at
//   ((d&1)*8+u+j)&15.  Both realized by pre-swizzling the DMA global source.
// Epilogue: after loop, S reused as per-wave [32][128] transpose staging ->
// full-line coalesced bf16x8 Opart stores (row-major [256][128], unchanged
// from R4 so reduce_kernel is untouched).
__global__ __launch_bounds__(512)
void attn_kernel(const __bf16* __restrict__ qb, const __bf16* __restrict__ kb,
                 const __bf16* __restrict__ vt,
                 __bf16* __restrict__ Opart, float* __restrict__ Lpart) {
  __shared__ __align__(16) __bf16 S[32768];   // 64KB

  const int tid   = threadIdx.x;
  const int lane  = tid & 63;
  const int w     = tid >> 6;        // 0..7
  const int l31   = lane & 31;
  const int half  = lane >> 5;
  const int batch = blockIdx.y;
  const int xw    = blockIdx.x;

  // q0 such that q0*(q0+1)/2 <= xw < (q0+1)*(q0+2)/2
  int q0 = 0;
  while (q0 < 15 && xw >= (((q0 + 1) * (q0 + 2)) >> 1)) ++q0;
  const int split = xw - ((q0 * (q0 + 1)) >> 1);
  const int it0   = split * 4;          // exactly 4 tiles per work item
  const int it1   = it0 + 4;

  const int strip0 = q0 * 256 + w * 32;
  const size_t bbase = (size_t)batch * TSEQ;

  bf16x8 qf[8];
  {
    const __bf16* qr = qb + (bbase + strip0 + l31) * HS + half * 8;
#pragma unroll
    for (int kc = 0; kc < 8; ++kc) qf[kc] = *(const bf16x8*)(qr + kc * 16);
  }

  const __bf16* kbb = kb + bbase * HS;
  const __bf16* vbb = vt + (size_t)batch * HS * TSEQ;

  // Per-thread DMA: 2 K-instrs / 2 V-instrs per tile; dest linear, src swz.
  auto stageK = [&](int buf, int c0) {
#pragma unroll
    for (int i = 0; i < 2; ++i) {
      int idx = i * 512 + w * 64 + lane;          // 16B-unit index 0..1023
      int row = idx >> 4;
      int su  = ((idx & 15) - row) & 15;          // inverse rotation
      gload16(kbb + (size_t)(c0 + row) * HS + su * 8,
              S + buf * 8192 + (i * 512 + w * 64) * 8);
    }
  };
  auto stageV = [&](int buf, int c0) {
#pragma unroll
    for (int i = 0; i < 2; ++i) {
      int idx = i * 512 + w * 64 + lane;
      int j   = idx >> 4;                         // dim-pair row 0..63
      int qd  = ((idx & 15) - j) & 15;            // unit-in-row (pre-rot)
      int d   = 2 * j + (qd >> 3);
      int u   = qd & 7;
      gload16(vbb + (size_t)d * TSEQ + c0 + u * 8,
              S + 16384 + buf * 8192 + (i * 512 + w * 64) * 8);
    }
  };

  f32x16 o[4];
#pragma unroll
  for (int nt = 0; nt < 4; ++nt)
#pragma unroll
    for (int r = 0; r < 16; ++r) o[nt][r] = 0.f;
  float lsum = 0.f;

  int cur = 0;
  stageK(0, it0 * 64);
  stageV(0, it0 * 64);

  for (int it = it0; it < it1; ++it) {
    const int c0 = it * 64;
    const bool more = (it + 1 < it1);

    // K of tile `it` ready (own V still allowed in flight: vmcnt(2)).
    asm volatile("s_waitcnt vmcnt(2)" ::: "memory");
    __syncthreads();                              // barrier1
    if (more) stageK(cur ^ 1, c0 + 64);

    const bool active = (c0 <= strip0 + 31);
    i32x2 pkt[2][4];
#pragma unroll
    for (int t = 0; t < 2; ++t)
#pragma unroll
      for (int j = 0; j < 4; ++j) pkt[t][j] = (i32x2){0, 0};

    if (active) {
#pragma unroll
      for (int t = 0; t < 2; ++t) {
        if (c0 + t * 32 <= strip0 + 31) {
          f32x16 s;
#pragma unroll
          for (int r = 0; r < 16; ++r) s[r] = 0.f;
          __builtin_amdgcn_s_setprio(1);
#pragma unroll
          for (int kc = 0; kc < 8; ++kc) {
            int row = t * 32 + l31;
            bf16x8 kf = *(const bf16x8*)(
                S + cur * 8192 + row * 128 + (((2 * kc + half) + row) & 15) * 8);
            s = __builtin_amdgcn_mfma_f32_32x32x16_bf16(kf, qf[kc], s, 0, 0, 0);
          }
          __builtin_amdgcn_s_setprio(0);
          if (c0 + t * 32 + 31 > strip0) {
#pragma unroll
            for (int r = 0; r < 16; ++r) {
              int key = c0 + t * 32 + (r & 3) + 8 * (r >> 2) + 4 * half;
              if (key > strip0 + l31) s[r] = -INFINITY;
            }
          }
          float p[16], ps = 0.f;
#pragma unroll
          for (int r = 0; r < 16; ++r) { p[r] = fexp2(s[r]); ps += p[r]; }
          lsum += ps;
#pragma unroll
          for (int j = 0; j < 4; ++j) {
            bf16x4 t4;
#pragma unroll
            for (int d = 0; d < 4; ++d) t4[d] = f2b(p[4 * j + d]);
            pkt[t][j] = __builtin_bit_cast(i32x2, t4);
          }
        }
      }
    }

    // V of tile `it` ready (queue: [curV, nextK] -> vmcnt(2); last iter: 0).
    if (more) asm volatile("s_waitcnt vmcnt(2)" ::: "memory");
    else      asm volatile("s_waitcnt vmcnt(0)" ::: "memory");
    __syncthreads();                              // barrier2
    if (more) stageV(cur ^ 1, c0 + 64);

    if (active) {
#pragma unroll
      for (int kk = 0; kk < 4; ++kk) {
        int t = kk >> 1, lo = (kk & 1) * 2;
        i32x2 a = pkt[t][lo], b = pkt[t][lo + 1];
        i32x4 af4;
#if defined(__has_builtin) && __has_builtin(__builtin_amdgcn_permlane32_swap)
        {
          auto r0 = __builtin_amdgcn_permlane32_swap(a.x, b.x, false, false);
          auto r1 = __builtin_amdgcn_permlane32_swap(a.y, b.y, false, false);
          af4.x = r0[0]; af4.y = r1[0]; af4.z = r0[1]; af4.w = r1[1];
        }
#else
        {
          i32x2 ra, rb;
          ra.x = __shfl_xor(a.x, 32); ra.y = __shfl_xor(a.y, 32);
          rb.x = __shfl_xor(b.x, 32); rb.y = __shfl_xor(b.y, 32);
          af4.x = half ? rb.x : a.x;
          af4.y = half ? rb.y : a.y;
          af4.z = half ? b.x  : ra.x;
          af4.w = half ? b.y  : ra.y;
        }
#endif
        bf16x8 af = __builtin_bit_cast(bf16x8, af4);
        __builtin_amdgcn_s_setprio(1);
#pragma unroll
        for (int nt = 0; nt < 4; ++nt) {
          int d = nt * 32 + l31;
          int j = d >> 1;
          int phys = (((d & 1) * 8 + 2 * kk + half) + j) & 15;
          bf16x8 vf = *(const bf16x8*)(
              S + 16384 + cur * 8192 + j * 128 + phys * 8);
          o[nt] = __builtin_amdgcn_mfma_f32_32x32x16_bf16(af, vf, o[nt], 0, 0, 0);
        }
        __builtin_amdgcn_s_setprio(0);
      }
    }
    cur ^= 1;
  }

  // ---- epilogue: LDS transpose (per-wave 8KB region) + coalesced stores ----
  __syncthreads();                                // K/V LDS now dead
  __bf16* stg = S + w * 4096;                     // [32][128] bf16
#pragma unroll
  for (int r = 0; r < 16; ++r) {
    int srow = 4 * half + (r & 3) + 8 * (r >> 2);
#pragma unroll
    for (int nt = 0; nt < 4; ++nt)
      stg[srow * 128 + nt * 32 + l31] = f2b(o[nt][r]);
  }
  const size_t widx = (size_t)batch * NWORK + xw;
  __bf16* Op = Opart + widx * (256 * 128) + w * 32 * 128;
#pragma unroll
  for (int i = 0; i < 8; ++i) {
    bf16x8 vv = *(const bf16x8*)(stg + i * 512 + lane * 8);
    *(bf16x8*)(Op + i * 512 + lane * 8) = vv;
  }
  lsum += __shfl_xor(lsum, 32);
  if (half == 0) Lpart[widx * 256 + w * 32 + l31] = lsum;
}

// ---------------------------------------------------------------------------
// K4: reduce bf16 partials + normalize. grid (512, 4) x 256 thr.
__global__ __launch_bounds__(256)
void reduce_kernel(const __bf16* __restrict__ Opart, const float* __restrict__ Lpart,
                   float* __restrict__ out) {
  const int batch = blockIdx.y;
  const int rowg  = blockIdx.x * 8 + (threadIdx.x >> 5);   // 0..4095
  const int q0 = rowg >> 8;
  const int nsp = q0 + 1;
  const int off = (q0 * (q0 + 1)) >> 1;
  const size_t wbase = (size_t)batch * NWORK + off;
  const int row256 = rowg & 255;
  const int c0 = (threadIdx.x & 31) * 4;

  float l = 0.f;
  for (int s = 0; s < nsp; ++s) l += Lpart[(wbase + s) * 256 + row256];
  const float inv = 1.0f / l;

  const __bf16* op = Opart + wbase * (256 * 128) + row256 * 128 + c0;
  f32x4 a = {0.f, 0.f, 0.f, 0.f};
  for (int s = 0; s < nsp; ++s) {
    bf16x4 v = *(const bf16x4*)(op + (size_t)s * 256 * 128);
#pragma unroll
    for (int j = 0; j < 4; ++j) a[j] += (float)v[j];
  }
  a *= inv;
  *(f32x4*)(out + ((size_t)batch * TSEQ + rowg) * HS + c0) = a;
}

// ---------------------------------------------------------------------------
extern "C" void kernel_launch(void* const* d_in, const int* in_sizes, int n_in,
                              void* d_out, int out_size, void* d_ws, size_t ws_size,
                              hipStream_t stream) {
  const float* x  = (const float*)d_in[0];
  const float* Wq = (const float*)d_in[1];
  const float* Wk = (const float*)d_in[2];
  const float* Wv = (const float*)d_in[3];
  float* out = (float*)d_out;

  char* ws = (char*)d_ws;
  // Wt 768K | qb 4M | kb 4M | vt 4M | Opart(bf16) 35.65M | Lpart 557K
  __bf16* Wt = (__bf16*)ws;
  __bf16* qb = (__bf16*)(ws + 786432);
  __bf16* kb = (__bf16*)(ws + 786432 + 4194304);
  __bf16* vt = (__bf16*)(ws + 786432 + 2 * 4194304);
  __bf16* Opart = (__bf16*)(ws + 786432 + 3 * 4194304);
  float*  Lpart = (float*)(ws + 786432 + 3 * 4194304 +
                           (size_t)NBATCH * NWORK * 256 * 128 * 2);

  wtrans_kernel<<<dim3(64, 3), 256, 0, stream>>>(Wq, Wk, Wv, Wt);
  proj_kernel<<<dim3(768), 128, 0, stream>>>(x, Wt, qb, kb, vt);
  attn_kernel<<<dim3(NWORK, NBATCH), 512, 0, stream>>>(qb, kb, vt, Opart, Lpart);
  reduce_kernel<<<dim3(512, NBATCH), 256, 0, stream>>>(Opart, Lpart, out);
}